// Round 15
// baseline (320.285 us; speedup 1.0000x reference)
//
#include <hip/hip_runtime.h>
#include <hip/hip_bf16.h>
#include <climits>

#define N_NODES   100000
#define N_EDGES   1600000
#define D         64
#define N_GRAPHS  32
#define N_CLASSES 40
#define N_TILES   (N_NODES / 16)   // 6250 row-tiles of 16
#define TPW       2                // row-tiles per wave (gemm)
#define GEMM_WAVES ((N_TILES + TPW - 1) / TPW)        // 3125
#define GEMM_BLOCKS ((GEMM_WAVES + 3) / 4)            // 782

// bucketed edge partition (bucket = 128 consecutive dst nodes)
#define BKT_SHIFT 7
#define BKT_NODES 128
#define NB        ((N_NODES + BKT_NODES - 1) / BKT_NODES)   // 782
#define CHUNK     4096
#define NCHUNK    ((N_EDGES + CHUNK - 1) / CHUNK)           // 391
#define EPT       (CHUNK / 256)                             // 16 edges/thread

// feature-sliced layout: X[s][node][8], s in [0,8). slice array = 1.6 MB -> L2-resident.
#define NSLICE    8
#define SL_F      8                                          // features per slice
#define EDGE_CHUNKS ((N_NODES + 127) / 128)                  // 782 node-chunks of 128
#define EDGE_GRID (NSLICE * EDGE_CHUNKS)                     // 6256; slice = bid & 7 (XCD affinity)

typedef _Float16 f16_t;
typedef f16_t f16x8 __attribute__((ext_vector_type(8)));
typedef f16_t f16x4 __attribute__((ext_vector_type(4)));
typedef float  f32x4  __attribute__((ext_vector_type(4)));

// Monotone bijection float -> int (order-preserving for signed int compare).
__device__ __forceinline__ int f2ord(float f) {
    int i = __float_as_int(f);
    return (i >= 0) ? i : (i ^ 0x7FFFFFFF);
}
__device__ __forceinline__ float ord2f(int i) {
    int j = (i >= 0) ? i : (i ^ 0x7FFFFFFF);
    return __int_as_float(j);
}

__device__ __forceinline__ f16x8 shflxor8(f16x8 v, int mask) {
    union { f16x8 h; int i[4]; } u;
    u.h = v;
    #pragma unroll
    for (int d = 0; d < 4; ++d) u.i[d] = __shfl_xor(u.i[d], mask, 64);
    return u.h;
}

// ---------------- prep: f16 transposed weights + fused biases + small inits ----------------
__global__ __launch_bounds__(256) void k_prep(
    const float* __restrict__ tw, const float* __restrict__ pw,
    const float* __restrict__ tb, const float* __restrict__ pb,
    f16_t* __restrict__ wcat, float* __restrict__ bcat,
    int* __restrict__ bktcnt, int* __restrict__ hg)
{
    const int i = blockIdx.x * 256 + threadIdx.x;
    if (i < 3 * 128 * 64) {
        const int l = i >> 13;
        const int rem = i & 8191;
        const int n = rem >> 6;
        const int k = rem & 63;
        const float v = (n < D) ? tw[l * 4096 + k * D + n] : pw[l * 4096 + k * D + (n - D)];
        wcat[i] = (f16_t)v;
    }
    if (i < 3 * D) bcat[i] = tb[i] + pb[i];
    if (i < NB) bktcnt[i] = 0;
    if (i < N_GRAPHS * D) hg[i] = INT_MIN;
}

// ---------------- fused: layer-0 GEMM (sliced output) + bucket histogram ----------------
__global__ __launch_bounds__(256) void k_gemm0_hist(
    const float* __restrict__ hf,
    const f16_t* __restrict__ wcat, const float* __restrict__ bcat,
    f16_t* __restrict__ ts, f16_t* __restrict__ qs,       // sliced [8][N][8]
    const int* __restrict__ dst, int* __restrict__ bktcnt)
{
    __shared__ int l[NB];
    if (blockIdx.x >= GEMM_BLOCKS) {
        const int bb = blockIdx.x - GEMM_BLOCKS;
        for (int i = threadIdx.x; i < NB; i += 256) l[i] = 0;
        __syncthreads();
        const int base = bb * CHUNK;
        #pragma unroll
        for (int i = 0; i < EPT; ++i) {
            const int e = base + i * 256 + threadIdx.x;
            if (e < N_EDGES) atomicAdd(&l[dst[e] >> BKT_SHIFT], 1);
        }
        __syncthreads();
        for (int i = threadIdx.x; i < NB; i += 256)
            if (l[i]) atomicAdd(&bktcnt[i], l[i]);
        return;
    }
    const int lane = threadIdx.x & 63;
    const int wid  = blockIdx.x * 4 + (threadIdx.x >> 6);
    const int r16  = lane & 15;
    const int kg   = lane >> 4;
    const int koff = kg * 8;

    f16x8 bfrag[8][2];
    #pragma unroll
    for (int c = 0; c < 8; ++c)
        #pragma unroll
        for (int s = 0; s < 2; ++s)
            bfrag[c][s] = *(const f16x8*)&wcat[(c * 16 + r16) * D + s * 32 + koff];

    f32x4 bias4[4];
    #pragma unroll
    for (int c = 0; c < 4; ++c) bias4[c] = *(const f32x4*)&bcat[c * 16 + kg * 4];

    #pragma unroll
    for (int tt = 0; tt < TPW; ++tt) {
        const int tile = wid * TPW + tt;
        if (tile >= N_TILES) return;
        const long rowbase = (long)tile * 16;
        const long arow = rowbase + r16;

        f16x8 afrag[2];
        #pragma unroll
        for (int s = 0; s < 2; ++s) {
            const f32x4 v0 = *(const f32x4*)&hf[arow * D + s * 32 + koff];
            const f32x4 v1 = *(const f32x4*)&hf[arow * D + s * 32 + koff + 4];
            f16x8 a;
            a[0] = (f16_t)v0[0]; a[1] = (f16_t)v0[1];
            a[2] = (f16_t)v0[2]; a[3] = (f16_t)v0[3];
            a[4] = (f16_t)v1[0]; a[5] = (f16_t)v1[1];
            a[6] = (f16_t)v1[2]; a[7] = (f16_t)v1[3];
            afrag[s] = a;
        }

        const f32x4 zero = {0.0f, 0.0f, 0.0f, 0.0f};
        f32x4 acc[8];
        #pragma unroll
        for (int c = 0; c < 8; ++c) {
            acc[c] = __builtin_amdgcn_mfma_f32_16x16x32_f16(bfrag[c][0], afrag[0], zero, 0, 0, 0);
            acc[c] = __builtin_amdgcn_mfma_f32_16x16x32_f16(bfrag[c][1], afrag[1], acc[c], 0, 0, 0);
        }

        const long node = rowbase + r16;
        #pragma unroll
        for (int c = 0; c < 4; ++c) {
            f16x4 tv, qv;
            #pragma unroll
            for (int j = 0; j < 4; ++j) {
                const float tf = acc[c][j];
                tv[j] = (f16_t)tf;
                qv[j] = (f16_t)(acc[c + 4][j] - tf + bias4[c][j]);
            }
            const int slice = c * 2 + (kg >> 1);
            const int off   = (kg & 1) * 4;
            *(f16x4*)&ts[((long)slice * N_NODES + node) * SL_F + off] = tv;
            *(f16x4*)&qs[((long)slice * N_NODES + node) * SL_F + off] = qv;
        }
    }
}

// ---------------- CSR build (scan, scatter, sort) ----------------

__global__ __launch_bounds__(256) void k_bkt_scan(
    const int* __restrict__ bktcnt, int* __restrict__ boff, int* __restrict__ gcur,
    int* __restrict__ rowptr)
{
    __shared__ int s[256];
    const int t = threadIdx.x;
    int v[4], sum = 0;
    #pragma unroll
    for (int i = 0; i < 4; ++i) {
        const int idx = t * 4 + i;
        v[i] = (idx < NB) ? bktcnt[idx] : 0;
        sum += v[i];
    }
    s[t] = sum;
    __syncthreads();
    #pragma unroll
    for (int off = 1; off < 256; off <<= 1) {
        int x = (t >= off) ? s[t - off] : 0;
        __syncthreads();
        s[t] += x;
        __syncthreads();
    }
    int run = s[t] - sum;
    #pragma unroll
    for (int i = 0; i < 4; ++i) {
        const int idx = t * 4 + i;
        if (idx < NB) {
            boff[idx] = run;
            gcur[idx] = run;
        }
        run += v[i];
    }
    if (t == 255) {
        boff[NB] = N_EDGES;
        rowptr[N_NODES] = N_EDGES;
    }
}

__global__ __launch_bounds__(256) void k_bkt_scatter(
    const int* __restrict__ src, const int* __restrict__ dst,
    int* __restrict__ gcur, unsigned* __restrict__ bke)
{
    __shared__ int lcnt[NB];
    __shared__ int gb[NB];
    for (int i = threadIdx.x; i < NB; i += 256) lcnt[i] = 0;
    __syncthreads();
    const int base = blockIdx.x * CHUNK;
    unsigned pk[EPT], br[EPT];
    #pragma unroll
    for (int i = 0; i < EPT; ++i) {
        const int e = base + i * 256 + threadIdx.x;
        if (e < N_EDGES) {
            const int d = dst[e];
            const int b = d >> BKT_SHIFT;
            const int r = atomicAdd(&lcnt[b], 1);
            pk[i] = ((unsigned)(d & (BKT_NODES - 1)) << 17) | (unsigned)src[e];
            br[i] = ((unsigned)b << 13) | (unsigned)r;   // r < 4096
        } else {
            br[i] = 0xFFFFFFFFu;
        }
    }
    __syncthreads();
    for (int i = threadIdx.x; i < NB; i += 256) {
        const int c = lcnt[i];
        gb[i] = c ? atomicAdd(&gcur[i], c) : 0;
    }
    __syncthreads();
    #pragma unroll
    for (int i = 0; i < EPT; ++i) {
        if (br[i] != 0xFFFFFFFFu) {
            const int b = br[i] >> 13;
            const int r = br[i] & 8191;
            bke[gb[b] + r] = pk[i];
        }
    }
}

__global__ __launch_bounds__(256) void k_bkt_sort(
    const int* __restrict__ boff, const unsigned* __restrict__ bke,
    int* __restrict__ ebuf, int* __restrict__ rowptr)
{
    __shared__ int cnt[BKT_NODES];
    __shared__ int pfx[BKT_NODES];
    const int b = blockIdx.x;
    const int tid = threadIdx.x;
    const int beg = boff[b];
    const int end = boff[b + 1];

    if (tid < BKT_NODES) cnt[tid] = 0;
    __syncthreads();
    for (int e = beg + tid; e < end; e += 256)
        atomicAdd(&cnt[bke[e] >> 17], 1);
    __syncthreads();
    if (tid < BKT_NODES) pfx[tid] = cnt[tid];
    __syncthreads();
    #pragma unroll
    for (int off = 1; off < BKT_NODES; off <<= 1) {
        int x = 0;
        if (tid < BKT_NODES && tid >= off) x = pfx[tid - off];
        __syncthreads();
        if (tid < BKT_NODES) pfx[tid] += x;
        __syncthreads();
    }
    if (tid < BKT_NODES) {
        const int excl = pfx[tid] - cnt[tid];
        const int node = b * BKT_NODES + tid;
        if (node <= N_NODES) rowptr[node] = beg + excl;
        cnt[tid] = beg + excl;
    }
    __syncthreads();
    for (int e = beg + tid; e < end; e += 256) {
        const unsigned pk = bke[e];
        const int pos = atomicAdd(&cnt[pk >> 17], 1);
        ebuf[pos] = (int)(pk & 0x1FFFFu);
    }
}

// ---------------- node GEMM via MFMA (sliced in/out), operands swapped ----------------
__global__ __launch_bounds__(256) void k_gemm_mfma(
    const f16_t* __restrict__ as_in,      // sliced agg [8][N][8]
    const f16_t* __restrict__ wcat,       // [128][64] this layer
    const float* __restrict__ bcat,       // [64] this layer
    f16_t* __restrict__ ts, f16_t* __restrict__ qs)   // sliced out
{
    const int lane = threadIdx.x & 63;
    const int wid  = blockIdx.x * 4 + (threadIdx.x >> 6);
    const int r16  = lane & 15;
    const int kg   = lane >> 4;
    const int koff = kg * 8;

    f16x8 bfrag[8][2];
    #pragma unroll
    for (int c = 0; c < 8; ++c)
        #pragma unroll
        for (int s = 0; s < 2; ++s)
            bfrag[c][s] = *(const f16x8*)&wcat[(c * 16 + r16) * D + s * 32 + koff];

    f32x4 bias4[4];
    #pragma unroll
    for (int c = 0; c < 4; ++c) bias4[c] = *(const f32x4*)&bcat[c * 16 + kg * 4];

    #pragma unroll
    for (int tt = 0; tt < TPW; ++tt) {
        const int tile = wid * TPW + tt;
        if (tile >= N_TILES) return;
        const long rowbase = (long)tile * 16;
        const long arow = rowbase + r16;

        // sliced A: afrag[0] = slice kg, afrag[1] = slice 4+kg (16B rows)
        f16x8 afrag[2];
        afrag[0] = *(const f16x8*)&as_in[((long)kg * N_NODES + arow) * SL_F];
        afrag[1] = *(const f16x8*)&as_in[((long)(4 + kg) * N_NODES + arow) * SL_F];

        const f32x4 zero = {0.0f, 0.0f, 0.0f, 0.0f};
        f32x4 acc[8];
        #pragma unroll
        for (int c = 0; c < 8; ++c) {
            acc[c] = __builtin_amdgcn_mfma_f32_16x16x32_f16(bfrag[c][0], afrag[0], zero, 0, 0, 0);
            acc[c] = __builtin_amdgcn_mfma_f32_16x16x32_f16(bfrag[c][1], afrag[1], acc[c], 0, 0, 0);
        }

        const long node = rowbase + r16;
        #pragma unroll
        for (int c = 0; c < 4; ++c) {
            f16x4 tv, qv;
            #pragma unroll
            for (int j = 0; j < 4; ++j) {
                const float tf = acc[c][j];
                tv[j] = (f16_t)tf;
                qv[j] = (f16_t)(acc[c + 4][j] - tf + bias4[c][j]);
            }
            const int slice = c * 2 + (kg >> 1);
            const int off   = (kg & 1) * 4;
            *(f16x4*)&ts[((long)slice * N_NODES + node) * SL_F + off] = tv;
            *(f16x4*)&qs[((long)slice * N_NODES + node) * SL_F + off] = qv;
        }
    }
}

// ---------------- sliced gather-max: slice = bid&7 (XCD-L2 affinity) ----------------
// Block: 128 nodes x 1 slice. 8-lane group per node-set; lane j = edge index.
// Each lane loads one edge's 16B slice-row; shfl_xor(1,2,4) reduce -> row max.
// POOL=false: write sliced agg. POOL=true: block-staged pool into hg slice.
template <bool POOL>
__global__ __launch_bounds__(256) void k_edge_slice(
    const int* __restrict__ rowptr, const int* __restrict__ ebuf,
    const f16_t* __restrict__ ts, const f16_t* __restrict__ qs,  // sliced [8][N][8]
    f16_t* __restrict__ as_out,                                   // sliced agg
    const int* __restrict__ gid, int* __restrict__ hg)
{
    __shared__ int hl[N_GRAPHS * SL_F];   // 1 KB (POOL only)
    const int s     = blockIdx.x & 7;
    const int chunk = blockIdx.x >> 3;
    const int lane  = threadIdx.x & 63;
    const int wv    = threadIdx.x >> 6;
    const int grp   = lane >> 3;          // group 0..7 within wave
    const int j     = lane & 7;           // edge sub-index within group

    const f16_t* tsl = ts + (size_t)s * N_NODES * SL_F;
    const f16_t* qsl = qs + (size_t)s * N_NODES * SL_F;

    if (POOL) {
        for (int i = threadIdx.x; i < N_GRAPHS * SL_F; i += 256) hl[i] = INT_MIN;
        __syncthreads();
    }

    // 4 nodes per 8-lane group
    for (int nn = 0; nn < 4; ++nn) {
        const int node = chunk * 128 + (wv * 8 + grp) * 4 + nn;
        if (node < N_NODES) {
            const int beg = rowptr[node];
            const int end = rowptr[node + 1];
            f16x8 o;
            if (end == beg) {
                #pragma unroll
                for (int i = 0; i < 8; ++i) o[i] = (f16_t)0.0f;
            } else {
                const f16x8 qv = *(const f16x8*)&qsl[(long)node * SL_F];  // hoisted
                const int last = end - 1;
                // seed with 16 edges (2 per lane; clamped dups are no-ops under max)
                f16x8 m0 = *(const f16x8*)&tsl[(long)ebuf[min(beg + j,     last)] * SL_F];
                f16x8 m1 = *(const f16x8*)&tsl[(long)ebuf[min(beg + 8 + j, last)] * SL_F];
                for (int e0 = beg + 16; e0 < end; e0 += 16) {
                    const int ra = ebuf[min(e0 + j,     last)];
                    const int rb = ebuf[min(e0 + 8 + j, last)];
                    m0 = __builtin_elementwise_max(m0, *(const f16x8*)&tsl[(long)ra * SL_F]);
                    m1 = __builtin_elementwise_max(m1, *(const f16x8*)&tsl[(long)rb * SL_F]);
                }
                f16x8 m = __builtin_elementwise_max(m0, m1);
                m = __builtin_elementwise_max(m, shflxor8(m, 1));
                m = __builtin_elementwise_max(m, shflxor8(m, 2));
                m = __builtin_elementwise_max(m, shflxor8(m, 4));
                o = m + qv;
            }
            if (!POOL) {
                if (j == 0)
                    *(f16x8*)&as_out[((size_t)s * N_NODES + node) * SL_F] = o;
            } else {
                if (j == 0) {
                    const int g0 = gid[node];
                    #pragma unroll
                    for (int i = 0; i < 8; ++i)
                        atomicMax(&hl[g0 * SL_F + i], f2ord((float)o[i]));
                }
            }
        }
    }

    if (POOL) {
        __syncthreads();
        const int blo = chunk * 128;
        const int bhi = (blo + 127 < N_NODES - 1) ? blo + 127 : N_NODES - 1;
        const int glo = gid[blo];
        const int ghi = gid[bhi];
        const int cnt = (ghi - glo + 1) * SL_F;
        for (int i = threadIdx.x; i < cnt; i += 256) {
            const int v = hl[glo * SL_F + i];
            if (v != INT_MIN)
                atomicMax(&hg[(glo + i / SL_F) * D + s * SL_F + (i & 7)], v);
        }
    }
}

// ---------------- classifier ----------------
__global__ __launch_bounds__(256) void k_cls(
    const int* __restrict__ hg, const float* __restrict__ w,
    const float* __restrict__ b, float* __restrict__ out)
{
    __shared__ float s_h[N_GRAPHS * D];
    __shared__ float s_w[D * N_CLASSES];
    __shared__ float s_b[N_CLASSES];
    for (int i = threadIdx.x; i < N_GRAPHS * D; i += 256) s_h[i] = ord2f(hg[i]);
    for (int i = threadIdx.x; i < D * N_CLASSES; i += 256) s_w[i] = w[i];
    if (threadIdx.x < N_CLASSES) s_b[threadIdx.x] = b[threadIdx.x];
    __syncthreads();
    for (int o = threadIdx.x; o < N_GRAPHS * N_CLASSES; o += 256) {
        const int g = o / N_CLASSES;
        const int c = o % N_CLASSES;
        float acc = s_b[c];
        #pragma unroll
        for (int k = 0; k < D; ++k)
            acc = fmaf(s_h[g * D + k], s_w[k * N_CLASSES + c], acc);
        out[o] = acc;
    }
}

extern "C" void kernel_launch(void* const* d_in, const int* in_sizes, int n_in,
                              void* d_out, int out_size, void* d_ws, size_t ws_size,
                              hipStream_t stream) {
    const float* h       = (const float*)d_in[0];
    const int*   src     = (const int*)d_in[1];
    const int*   dst     = (const int*)d_in[2];
    const int*   gid     = (const int*)d_in[3];
    const float* theta_w = (const float*)d_in[4];
    const float* theta_b = (const float*)d_in[5];
    const float* phi_w   = (const float*)d_in[6];
    const float* phi_b   = (const float*)d_in[7];
    const float* cls_w   = (const float*)d_in[8];
    const float* cls_b   = (const float*)d_in[9];
    float* out = (float*)d_out;

    const size_t NF = (size_t)N_NODES * D;
    char* p = (char*)d_ws;
    f16_t* ts1   = (f16_t*)p;   p += NF * 2;                 // 12.8 MB (sliced)
    f16_t* qs1   = (f16_t*)p;   p += NF * 2;
    f16_t* ts2   = (f16_t*)p;   p += NF * 2;
    f16_t* qs2   = (f16_t*)p;   p += NF * 2;
    f16_t* asg   = (f16_t*)p;   p += NF * 2;                 // sliced agg
    f16_t* wcat  = (f16_t*)p;   p += 3 * 128 * D * 2;        // 48 KB
    float*  bcat = (float*)p;   p += 3 * D * 4;
    unsigned* bke = (unsigned*)p; p += (size_t)N_EDGES * 4;  // 6.4 MB
    int* ebuf    = (int*)p;     p += (size_t)N_EDGES * 4;    // 6.4 MB
    int* rowptr  = (int*)p;     p += (N_NODES + 1) * 4;
    int* bktcnt  = (int*)p;     p += NB * 4;
    int* boff    = (int*)p;     p += (NB + 1) * 4;
    int* gcur    = (int*)p;     p += NB * 4;
    int* hg      = (int*)p;     p += N_GRAPHS * D * 4;
    const size_t need = (size_t)(p - (char*)d_ws);
    if (ws_size < need) {
        hipMemsetAsync(d_out, 0, (size_t)out_size * sizeof(float), stream);
        return;
    }

    // ---- prep (weights, biases, bktcnt=0, hg=INT_MIN) ----
    k_prep<<<96, 256, 0, stream>>>(theta_w, phi_w, theta_b, phi_b, wcat, bcat, bktcnt, hg);

    // ---- layer-0 GEMM (sliced out) fused with bucket histogram ----
    k_gemm0_hist<<<GEMM_BLOCKS + NCHUNK, 256, 0, stream>>>(h, wcat, bcat, ts1, qs1, dst, bktcnt);

    // ---- CSR build ----
    k_bkt_scan<<<1, 256, 0, stream>>>(bktcnt, boff, gcur, rowptr);
    k_bkt_scatter<<<NCHUNK, 256, 0, stream>>>(src, dst, gcur, bke);
    k_bkt_sort<<<NB, 256, 0, stream>>>(boff, bke, ebuf, rowptr);

    // ---- layer 1: sliced edge -> agg, gemm -> ts2/qs2 ----
    k_edge_slice<false><<<EDGE_GRID, 256, 0, stream>>>(rowptr, ebuf, ts1, qs1, asg, nullptr, nullptr);
    k_gemm_mfma<<<GEMM_BLOCKS, 256, 0, stream>>>(asg, wcat + 128 * D, bcat + D, ts2, qs2);

    // ---- layer 2: sliced edge -> agg, gemm -> ts1/qs1 ----
    k_edge_slice<false><<<EDGE_GRID, 256, 0, stream>>>(rowptr, ebuf, ts2, qs2, asg, nullptr, nullptr);
    k_gemm_mfma<<<GEMM_BLOCKS, 256, 0, stream>>>(asg, wcat + 2 * 128 * D, bcat + 2 * D, ts1, qs1);

    // ---- layer 3: sliced edge fused with block-staged pool ----
    k_edge_slice<true><<<EDGE_GRID, 256, 0, stream>>>(rowptr, ebuf, ts1, qs1, nullptr, gid, hg);

    // ---- classifier ----
    k_cls<<<1, 256, 0, stream>>>(hg, cls_w, cls_b, out);
}

// Round 16
// 200.299 us; speedup vs baseline: 1.5990x; 1.5990x over previous
//
#include <hip/hip_runtime.h>
#include <hip/hip_bf16.h>
#include <climits>

#define N_NODES   100000
#define N_EDGES   1600000
#define D         64
#define N_GRAPHS  32
#define N_CLASSES 40
#define N_TILES   (N_NODES / 16)   // 6250 row-tiles of 16
#define TPW       2                // row-tiles per wave (layer-0 gemm)
#define GEMM_WAVES ((N_TILES + TPW - 1) / TPW)        // 3125
#define GEMM_BLOCKS ((GEMM_WAVES + 3) / 4)            // 782

// bucketed edge partition (bucket = 128 consecutive dst nodes)
#define BKT_SHIFT 7
#define BKT_NODES 128
#define NB        ((N_NODES + BKT_NODES - 1) / BKT_NODES)   // 782
#define CHUNK     4096
#define NCHUNK    ((N_EDGES + CHUNK - 1) / CHUNK)           // 391
#define EPT       (CHUNK / 256)                             // 16 edges/thread

typedef _Float16 f16_t;
typedef f16_t f16x8 __attribute__((ext_vector_type(8)));
typedef f16_t f16x4 __attribute__((ext_vector_type(4)));
typedef float  f32x4  __attribute__((ext_vector_type(4)));

// Monotone bijection float -> int (order-preserving for signed int compare).
__device__ __forceinline__ int f2ord(float f) {
    int i = __float_as_int(f);
    return (i >= 0) ? i : (i ^ 0x7FFFFFFF);
}
__device__ __forceinline__ float ord2f(int i) {
    int j = (i >= 0) ? i : (i ^ 0x7FFFFFFF);
    return __int_as_float(j);
}

__device__ __forceinline__ f16x8 shflxor8(f16x8 v, int mask) {
    union { f16x8 h; int i[4]; } u;
    u.h = v;
    #pragma unroll
    for (int d = 0; d < 4; ++d) u.i[d] = __shfl_xor(u.i[d], mask, 64);
    return u.h;
}

// ---------------- prep: f16 transposed weights + fused biases + all small inits ----------------
__global__ __launch_bounds__(256) void k_prep(
    const float* __restrict__ tw, const float* __restrict__ pw,
    const float* __restrict__ tb, const float* __restrict__ pb,
    f16_t* __restrict__ wcat, float* __restrict__ bcat,
    int* __restrict__ bktcnt, int* __restrict__ hg)
{
    const int i = blockIdx.x * 256 + threadIdx.x;
    if (i < 3 * 128 * 64) {
        const int l = i >> 13;
        const int rem = i & 8191;
        const int n = rem >> 6;
        const int k = rem & 63;
        const float v = (n < D) ? tw[l * 4096 + k * D + n] : pw[l * 4096 + k * D + (n - D)];
        wcat[i] = (f16_t)v;
    }
    if (i < 3 * D) bcat[i] = tb[i] + pb[i];
    if (i < NB) bktcnt[i] = 0;
    if (i < N_GRAPHS * D) hg[i] = INT_MIN;
}

// ---------------- fused: layer-0 GEMM (blocks < GEMM_BLOCKS) + bucket histogram ----------------
__global__ __launch_bounds__(256) void k_gemm0_hist(
    const float* __restrict__ hf,
    const f16_t* __restrict__ wcat, const float* __restrict__ bcat,
    f16_t* __restrict__ t, f16_t* __restrict__ q,
    const int* __restrict__ dst, int* __restrict__ bktcnt)
{
    __shared__ int l[NB];
    if (blockIdx.x >= GEMM_BLOCKS) {
        // ---- histogram path ----
        const int bb = blockIdx.x - GEMM_BLOCKS;
        for (int i = threadIdx.x; i < NB; i += 256) l[i] = 0;
        __syncthreads();
        const int base = bb * CHUNK;
        #pragma unroll
        for (int i = 0; i < EPT; ++i) {
            const int e = base + i * 256 + threadIdx.x;
            if (e < N_EDGES) atomicAdd(&l[dst[e] >> BKT_SHIFT], 1);
        }
        __syncthreads();
        for (int i = threadIdx.x; i < NB; i += 256)
            if (l[i]) atomicAdd(&bktcnt[i], l[i]);
        return;
    }
    // ---- GEMM path (f32 input), operands swapped: lane holds node = lane&15 ----
    const int lane = threadIdx.x & 63;
    const int wid  = blockIdx.x * 4 + (threadIdx.x >> 6);
    const int r16  = lane & 15;
    const int kg   = lane >> 4;
    const int koff = kg * 8;

    f16x8 bfrag[8][2];
    #pragma unroll
    for (int c = 0; c < 8; ++c)
        #pragma unroll
        for (int s = 0; s < 2; ++s)
            bfrag[c][s] = *(const f16x8*)&wcat[(c * 16 + r16) * D + s * 32 + koff];

    f32x4 bias4[4];
    #pragma unroll
    for (int c = 0; c < 4; ++c) bias4[c] = *(const f32x4*)&bcat[c * 16 + kg * 4];

    #pragma unroll
    for (int tt = 0; tt < TPW; ++tt) {
        const int tile = wid * TPW + tt;
        if (tile >= N_TILES) return;
        const long rowbase = (long)tile * 16;
        const long arow = rowbase + r16;

        f16x8 afrag[2];
        #pragma unroll
        for (int s = 0; s < 2; ++s) {
            const f32x4 v0 = *(const f32x4*)&hf[arow * D + s * 32 + koff];
            const f32x4 v1 = *(const f32x4*)&hf[arow * D + s * 32 + koff + 4];
            f16x8 a;
            a[0] = (f16_t)v0[0]; a[1] = (f16_t)v0[1];
            a[2] = (f16_t)v0[2]; a[3] = (f16_t)v0[3];
            a[4] = (f16_t)v1[0]; a[5] = (f16_t)v1[1];
            a[6] = (f16_t)v1[2]; a[7] = (f16_t)v1[3];
            afrag[s] = a;
        }

        const f32x4 zero = {0.0f, 0.0f, 0.0f, 0.0f};
        f32x4 acc[8];
        #pragma unroll
        for (int c = 0; c < 8; ++c) {
            acc[c] = __builtin_amdgcn_mfma_f32_16x16x32_f16(bfrag[c][0], afrag[0], zero, 0, 0, 0);
            acc[c] = __builtin_amdgcn_mfma_f32_16x16x32_f16(bfrag[c][1], afrag[1], acc[c], 0, 0, 0);
        }

        const long node = rowbase + r16;
        #pragma unroll
        for (int c = 0; c < 4; ++c) {
            f16x4 tv, qv;
            #pragma unroll
            for (int j = 0; j < 4; ++j) {
                const float tf = acc[c][j];
                tv[j] = (f16_t)tf;
                qv[j] = (f16_t)(acc[c + 4][j] - tf + bias4[c][j]);
            }
            *(f16x4*)&t[node * D + c * 16 + kg * 4] = tv;
            *(f16x4*)&q[node * D + c * 16 + kg * 4] = qv;
        }
    }
}

// ---------------- CSR build (scan, scatter, sort) ----------------

__global__ __launch_bounds__(256) void k_bkt_scan(
    const int* __restrict__ bktcnt, int* __restrict__ boff, int* __restrict__ gcur,
    int* __restrict__ rowptr)
{
    __shared__ int s[256];
    const int t = threadIdx.x;
    int v[4], sum = 0;
    #pragma unroll
    for (int i = 0; i < 4; ++i) {
        const int idx = t * 4 + i;
        v[i] = (idx < NB) ? bktcnt[idx] : 0;
        sum += v[i];
    }
    s[t] = sum;
    __syncthreads();
    #pragma unroll
    for (int off = 1; off < 256; off <<= 1) {
        int x = (t >= off) ? s[t - off] : 0;
        __syncthreads();
        s[t] += x;
        __syncthreads();
    }
    int run = s[t] - sum;
    #pragma unroll
    for (int i = 0; i < 4; ++i) {
        const int idx = t * 4 + i;
        if (idx < NB) {
            boff[idx] = run;
            gcur[idx] = run;
        }
        run += v[i];
    }
    if (t == 255) {
        boff[NB] = N_EDGES;
        rowptr[N_NODES] = N_EDGES;
    }
}

// Pass A: scatter edges into bucket regions. Block-local ranks via LDS, one global
// atomicAdd per (block,bucket) reserves a contiguous run -> write locality.
// Packed edge: (dst & 127) << 17 | src   (src < 2^17).
__global__ __launch_bounds__(256) void k_bkt_scatter(
    const int* __restrict__ src, const int* __restrict__ dst,
    int* __restrict__ gcur, unsigned* __restrict__ bke)
{
    __shared__ int lcnt[NB];
    __shared__ int gb[NB];
    for (int i = threadIdx.x; i < NB; i += 256) lcnt[i] = 0;
    __syncthreads();
    const int base = blockIdx.x * CHUNK;
    unsigned pk[EPT], br[EPT];
    #pragma unroll
    for (int i = 0; i < EPT; ++i) {
        const int e = base + i * 256 + threadIdx.x;
        if (e < N_EDGES) {
            const int d = dst[e];
            const int b = d >> BKT_SHIFT;
            const int r = atomicAdd(&lcnt[b], 1);
            pk[i] = ((unsigned)(d & (BKT_NODES - 1)) << 17) | (unsigned)src[e];
            br[i] = ((unsigned)b << 13) | (unsigned)r;   // r < 4096
        } else {
            br[i] = 0xFFFFFFFFu;
        }
    }
    __syncthreads();
    for (int i = threadIdx.x; i < NB; i += 256) {
        const int c = lcnt[i];
        gb[i] = c ? atomicAdd(&gcur[i], c) : 0;
    }
    __syncthreads();
    #pragma unroll
    for (int i = 0; i < EPT; ++i) {
        if (br[i] != 0xFFFFFFFFu) {
            const int b = br[i] >> 13;
            const int r = br[i] & 8191;
            bke[gb[b] + r] = pk[i];
        }
    }
}

// Pass B: in-bucket counting sort -> per-node CSR order + rowptr.
__global__ __launch_bounds__(256) void k_bkt_sort(
    const int* __restrict__ boff, const unsigned* __restrict__ bke,
    int* __restrict__ ebuf, int* __restrict__ rowptr)
{
    __shared__ int cnt[BKT_NODES];   // histogram, then cursor
    __shared__ int pfx[BKT_NODES];   // inclusive scan
    const int b = blockIdx.x;
    const int tid = threadIdx.x;
    const int beg = boff[b];
    const int end = boff[b + 1];

    if (tid < BKT_NODES) cnt[tid] = 0;
    __syncthreads();
    for (int e = beg + tid; e < end; e += 256)
        atomicAdd(&cnt[bke[e] >> 17], 1);
    __syncthreads();
    if (tid < BKT_NODES) pfx[tid] = cnt[tid];
    __syncthreads();
    #pragma unroll
    for (int off = 1; off < BKT_NODES; off <<= 1) {
        int x = 0;
        if (tid < BKT_NODES && tid >= off) x = pfx[tid - off];
        __syncthreads();
        if (tid < BKT_NODES) pfx[tid] += x;
        __syncthreads();
    }
    if (tid < BKT_NODES) {
        const int excl = pfx[tid] - cnt[tid];
        const int node = b * BKT_NODES + tid;
        if (node <= N_NODES) rowptr[node] = beg + excl;
        cnt[tid] = beg + excl;
    }
    __syncthreads();
    for (int e = beg + tid; e < end; e += 256) {
        const unsigned pk = bke[e];
        const int pos = atomicAdd(&cnt[pk >> 17], 1);
        ebuf[pos] = (int)(pk & 0x1FFFFu);
    }
}

// ---------------- FUSED edge+next-layer-GEMM: 32 nodes/block ----------------
// Phase A: gather-max into LDS agg (4 KB, XOR-swizzled). Phase B: MFMA gemm for
// those 32 nodes using NEXT layer's weights. Skips the global agg round-trip.
__global__ __launch_bounds__(256) void k_edge_gemm(
    const int* __restrict__ rowptr, const int* __restrict__ ebuf,
    const f16_t* __restrict__ t_in, const f16_t* __restrict__ q_in,
    const f16_t* __restrict__ wcat_next, const float* __restrict__ bcat_next,
    f16_t* __restrict__ t_out, f16_t* __restrict__ q_out)
{
    __shared__ f16_t sAgg[32 * D];   // 4 KB
    const int lane = threadIdx.x & 63;
    const int wv   = threadIdx.x >> 6;
    const int grp  = lane >> 3;
    const int g    = lane & 7;
    const int ln   = wv * 8 + grp;               // local node 0..31
    const int node = blockIdx.x * 32 + ln;

    // ---- preload next-layer weight fragments (hide latency under gather) ----
    const int r16  = lane & 15;
    const int kg   = lane >> 4;
    const int koff = kg * 8;
    const int cbase = (wv & 1) * 2;              // this wave's t-cols: cbase, cbase+1
    f16x8 bfrag[4][2];                           // [i<2: t-col i][khalf], [i+2: p-col i]
    #pragma unroll
    for (int i = 0; i < 2; ++i)
        #pragma unroll
        for (int s = 0; s < 2; ++s) {
            bfrag[i][s]     = *(const f16x8*)&wcat_next[((cbase + i) * 16 + r16) * D + s * 32 + koff];
            bfrag[i + 2][s] = *(const f16x8*)&wcat_next[((cbase + i + 4) * 16 + r16) * D + s * 32 + koff];
        }
    f32x4 bias4[2];
    #pragma unroll
    for (int i = 0; i < 2; ++i) bias4[i] = *(const f32x4*)&bcat_next[(cbase + i) * 16 + kg * 4];

    // ---- Phase A: gather-max for this thread's node (8-lane group) ----
    const int beg = rowptr[node];
    const int end = rowptr[node + 1];
    f16x8 o;
    if (end == beg) {
        #pragma unroll
        for (int i = 0; i < 8; ++i) o[i] = (f16_t)0.0f;
    } else {
        const f16x8 qv = *(const f16x8*)&q_in[(long)node * D + g * 8];
        const int last = end - 1;
        f16x8 m0, m1;
        {
            int r[8];
            #pragma unroll
            for (int u = 0; u < 8; ++u) r[u] = ebuf[min(beg + u, last)];
            f16x8 v[8];
            #pragma unroll
            for (int u = 0; u < 8; ++u) v[u] = *(const f16x8*)&t_in[((long)r[u] << 6) + g * 8];
            m0 = __builtin_elementwise_max(__builtin_elementwise_max(v[0], v[1]),
                                           __builtin_elementwise_max(v[2], v[3]));
            m1 = __builtin_elementwise_max(__builtin_elementwise_max(v[4], v[5]),
                                           __builtin_elementwise_max(v[6], v[7]));
        }
        for (int e0 = beg + 8; e0 < end; e0 += 8) {
            int r[8];
            #pragma unroll
            for (int u = 0; u < 8; ++u) r[u] = ebuf[min(e0 + u, last)];
            f16x8 v[8];
            #pragma unroll
            for (int u = 0; u < 8; ++u) v[u] = *(const f16x8*)&t_in[((long)r[u] << 6) + g * 8];
            m0 = __builtin_elementwise_max(m0,
                     __builtin_elementwise_max(__builtin_elementwise_max(v[0], v[1]),
                                               __builtin_elementwise_max(v[2], v[3])));
            m1 = __builtin_elementwise_max(m1,
                     __builtin_elementwise_max(__builtin_elementwise_max(v[4], v[5]),
                                               __builtin_elementwise_max(v[6], v[7])));
        }
        o = __builtin_elementwise_max(m0, m1) + qv;
    }
    *(f16x8*)&sAgg[ln * D + ((g ^ (ln & 7)) << 3)] = o;   // swizzled chunk
    __syncthreads();

    // ---- Phase B: gemm for this block's 32 nodes (wave -> node-tile wv>>1, cols cbase..cbase+1) ----
    const int nt = wv >> 1;
    const int rowA = nt * 16 + r16;
    f16x8 afrag[2];
    afrag[0] = *(const f16x8*)&sAgg[rowA * D + (((kg)     ^ (r16 & 7)) << 3)];  // chunk kg
    afrag[1] = *(const f16x8*)&sAgg[rowA * D + (((4 ^ kg) ^ (r16 & 7)) << 3)];  // chunk 4+kg

    const long nodeB = (long)blockIdx.x * 32 + nt * 16 + r16;
    const f32x4 zero = {0.0f, 0.0f, 0.0f, 0.0f};
    #pragma unroll
    for (int i = 0; i < 2; ++i) {
        f32x4 acc_t, acc_p;
        acc_t = __builtin_amdgcn_mfma_f32_16x16x32_f16(bfrag[i][0],     afrag[0], zero,  0, 0, 0);
        acc_t = __builtin_amdgcn_mfma_f32_16x16x32_f16(bfrag[i][1],     afrag[1], acc_t, 0, 0, 0);
        acc_p = __builtin_amdgcn_mfma_f32_16x16x32_f16(bfrag[i + 2][0], afrag[0], zero,  0, 0, 0);
        acc_p = __builtin_amdgcn_mfma_f32_16x16x32_f16(bfrag[i + 2][1], afrag[1], acc_p, 0, 0, 0);
        const int c = cbase + i;
        f16x4 tv, qv2;
        #pragma unroll
        for (int j = 0; j < 4; ++j) {
            const float tf = acc_t[j];
            tv[j]  = (f16_t)tf;
            qv2[j] = (f16_t)(acc_p[j] - tf + bias4[i][j]);
        }
        *(f16x4*)&t_out[nodeB * D + c * 16 + kg * 4] = tv;
        *(f16x4*)&q_out[nodeB * D + c * 16 + kg * 4] = qv2;
    }
}

// ---------------- FUSED last edge pass + block-staged pool ----------------
// 32 nodes/block. Computes the layer-3 output per node, reduces wave-locally
// (graphs uniform per wave ~99.7%: shfl_xor; else per-thread LDS atomics) into
// an LDS hg replica, then flushes only the 1-2 graphs this block touches.
// agg never hits global memory.
__global__ __launch_bounds__(256) void k_edge_pool(
    const int* __restrict__ rowptr, const int* __restrict__ ebuf,
    const f16_t* __restrict__ t, const f16_t* __restrict__ q,
    const int* __restrict__ gid, int* __restrict__ hg)
{
    __shared__ int hl[N_GRAPHS * D];   // 8 KB ordered-int replica
    for (int i = threadIdx.x; i < N_GRAPHS * D; i += 256) hl[i] = INT_MIN;
    __syncthreads();

    const int lane = threadIdx.x & 63;
    const int grp  = lane >> 3;
    const int g    = lane & 7;
    const int node = blockIdx.x * 32 + (threadIdx.x >> 6) * 8 + grp;
    const int beg = rowptr[node];
    const int end = rowptr[node + 1];

    f16x8 o;
    if (end == beg) {               // deg-0: zero row still participates in pool
        #pragma unroll
        for (int i = 0; i < 8; ++i) o[i] = (f16_t)0.0f;
    } else {
        const f16x8 qv = *(const f16x8*)&q[(long)node * D + g * 8];
        const int last = end - 1;
        f16x8 m0, m1;
        {
            int r[8];
            #pragma unroll
            for (int u = 0; u < 8; ++u) r[u] = ebuf[min(beg + u, last)];
            f16x8 v[8];
            #pragma unroll
            for (int u = 0; u < 8; ++u) v[u] = *(const f16x8*)&t[((long)r[u] << 6) + g * 8];
            m0 = __builtin_elementwise_max(__builtin_elementwise_max(v[0], v[1]),
                                           __builtin_elementwise_max(v[2], v[3]));
            m1 = __builtin_elementwise_max(__builtin_elementwise_max(v[4], v[5]),
                                           __builtin_elementwise_max(v[6], v[7]));
        }
        for (int e0 = beg + 8; e0 < end; e0 += 8) {
            int r[8];
            #pragma unroll
            for (int u = 0; u < 8; ++u) r[u] = ebuf[min(e0 + u, last)];
            f16x8 v[8];
            #pragma unroll
            for (int u = 0; u < 8; ++u) v[u] = *(const f16x8*)&t[((long)r[u] << 6) + g * 8];
            m0 = __builtin_elementwise_max(m0,
                     __builtin_elementwise_max(__builtin_elementwise_max(v[0], v[1]),
                                               __builtin_elementwise_max(v[2], v[3])));
            m1 = __builtin_elementwise_max(m1,
                     __builtin_elementwise_max(__builtin_elementwise_max(v[4], v[5]),
                                               __builtin_elementwise_max(v[6], v[7])));
        }
        o = __builtin_elementwise_max(m0, m1) + qv;
    }

    // ---- wave-local pool into LDS replica ----
    const int g0 = gid[node];
    const int gf = __shfl(g0, 0);
    const int gl = __shfl(g0, 63);
    if (gf == gl) {                 // whole wave in one graph
        f16x8 m = o;
        m = __builtin_elementwise_max(m, shflxor8(m, 8));
        m = __builtin_elementwise_max(m, shflxor8(m, 16));
        m = __builtin_elementwise_max(m, shflxor8(m, 32));
        if (grp == 0) {
            #pragma unroll
            for (int i = 0; i < 8; ++i)
                atomicMax(&hl[gf * D + g * 8 + i], f2ord((float)m[i]));
        }
    } else {                        // graph boundary inside the wave
        #pragma unroll
        for (int i = 0; i < 8; ++i)
            atomicMax(&hl[g0 * D + g * 8 + i], f2ord((float)o[i]));
    }
    __syncthreads();

    // ---- flush the 1-2 graphs this block touched ----
    const int blo = blockIdx.x * 32;
    const int bhi = (blo + 31 < N_NODES - 1) ? blo + 31 : N_NODES - 1;
    const int glo = gid[blo];
    const int ghi = gid[bhi];
    const int cnt = (ghi - glo + 1) * D;
    for (int i = threadIdx.x; i < cnt; i += 256) {
        const int v = hl[glo * D + i];
        if (v != INT_MIN) atomicMax(&hg[glo * D + i], v);
    }
}

// ---------------- classifier ----------------
__global__ __launch_bounds__(256) void k_cls(
    const int* __restrict__ hg, const float* __restrict__ w,
    const float* __restrict__ b, float* __restrict__ out)
{
    __shared__ float s_h[N_GRAPHS * D];
    __shared__ float s_w[D * N_CLASSES];
    __shared__ float s_b[N_CLASSES];
    for (int i = threadIdx.x; i < N_GRAPHS * D; i += 256) s_h[i] = ord2f(hg[i]);
    for (int i = threadIdx.x; i < D * N_CLASSES; i += 256) s_w[i] = w[i];
    if (threadIdx.x < N_CLASSES) s_b[threadIdx.x] = b[threadIdx.x];
    __syncthreads();
    for (int o = threadIdx.x; o < N_GRAPHS * N_CLASSES; o += 256) {
        const int g = o / N_CLASSES;
        const int c = o % N_CLASSES;
        float acc = s_b[c];
        #pragma unroll
        for (int k = 0; k < D; ++k)
            acc = fmaf(s_h[g * D + k], s_w[k * N_CLASSES + c], acc);
        out[o] = acc;
    }
}

extern "C" void kernel_launch(void* const* d_in, const int* in_sizes, int n_in,
                              void* d_out, int out_size, void* d_ws, size_t ws_size,
                              hipStream_t stream) {
    const float* h       = (const float*)d_in[0];
    const int*   src     = (const int*)d_in[1];
    const int*   dst     = (const int*)d_in[2];
    const int*   gid     = (const int*)d_in[3];
    const float* theta_w = (const float*)d_in[4];
    const float* theta_b = (const float*)d_in[5];
    const float* phi_w   = (const float*)d_in[6];
    const float* phi_b   = (const float*)d_in[7];
    const float* cls_w   = (const float*)d_in[8];
    const float* cls_b   = (const float*)d_in[9];
    float* out = (float*)d_out;

    const size_t NF = (size_t)N_NODES * D;
    char* p = (char*)d_ws;
    f16_t* t1    = (f16_t*)p;   p += NF * 2;                 // 12.8 MB
    f16_t* q1    = (f16_t*)p;   p += NF * 2;                 // 12.8 MB
    f16_t* t2    = (f16_t*)p;   p += NF * 2;                 // 12.8 MB (double-buffer t/q)
    f16_t* q2    = (f16_t*)p;   p += NF * 2;                 // 12.8 MB
    f16_t* wcat  = (f16_t*)p;   p += 3 * 128 * D * 2;        // 48 KB
    float*  bcat = (float*)p;   p += 3 * D * 4;
    unsigned* bke = (unsigned*)p; p += (size_t)N_EDGES * 4;  // 6.4 MB
    int* ebuf    = (int*)p;     p += (size_t)N_EDGES * 4;    // 6.4 MB
    int* rowptr  = (int*)p;     p += (N_NODES + 1) * 4;
    int* bktcnt  = (int*)p;     p += NB * 4;
    int* boff    = (int*)p;     p += (NB + 1) * 4;
    int* gcur    = (int*)p;     p += NB * 4;
    int* hg      = (int*)p;     p += N_GRAPHS * D * 4;
    const size_t need = (size_t)(p - (char*)d_ws);
    if (ws_size < need) {
        hipMemsetAsync(d_out, 0, (size_t)out_size * sizeof(float), stream);
        return;
    }

    const int FUSE_GRID = N_NODES / 32;            // 3125 (32 nodes/block)

    // ---- prep (weights, biases, bktcnt=0, hg=INT_MIN) ----
    k_prep<<<96, 256, 0, stream>>>(theta_w, phi_w, theta_b, phi_b, wcat, bcat, bktcnt, hg);

    // ---- layer-0 GEMM fused with bucket histogram ----
    k_gemm0_hist<<<GEMM_BLOCKS + NCHUNK, 256, 0, stream>>>(h, wcat, bcat, t1, q1, dst, bktcnt);

    // ---- CSR build ----
    k_bkt_scan<<<1, 256, 0, stream>>>(bktcnt, boff, gcur, rowptr);
    k_bkt_scatter<<<NCHUNK, 256, 0, stream>>>(src, dst, gcur, bke);
    k_bkt_sort<<<NB, 256, 0, stream>>>(boff, bke, ebuf, rowptr);

    // ---- fused edge(l)+gemm(l+1) for layers 1->2 and 2->3 ----
    k_edge_gemm<<<FUSE_GRID, 256, 0, stream>>>(
        rowptr, ebuf, t1, q1, wcat + 128 * D, bcat + D, t2, q2);
    k_edge_gemm<<<FUSE_GRID, 256, 0, stream>>>(
        rowptr, ebuf, t2, q2, wcat + 2 * 128 * D, bcat + 2 * D, t1, q1);

    // ---- last edge pass fused with block-staged pool ----
    k_edge_pool<<<FUSE_GRID, 256, 0, stream>>>(rowptr, ebuf, t1, q1, gid, hg);

    // ---- classifier ----
    k_cls<<<1, 256, 0, stream>>>(hg, cls_w, cls_b, out);
}